// Round 5
// baseline (2301.536 us; speedup 1.0000x reference)
//
#include <hip/hip_runtime.h>
#include <cstdint>

// ---------------------------------------------------------------------------
// JukeboxAutoEncoder fp32, round 5.
// conv3: lane = t, wave owns 16 wave-uniform output channels (co0 via
// readfirstlane) -> weights via scalar loads, 96 FMA per 48 weight floats.
// vq_dots: 2 tokens x 2 accumulators per inner iteration (4 indep FMA chains).
// Output layout (flat f32): x_hat[262144] | loss_vq[1] | ids[32768] | sim[16777216]
// ---------------------------------------------------------------------------

#define OFF_LOSS 262144
#define OFF_IDS  262145
#define OFF_SIM  294913

// ---------------- down0: (B,65536,1) -> (B,32768,64), K=4 stride2, relu ----
__global__ __launch_bounds__(256) void down0_kernel(
    const float* __restrict__ x, const float* __restrict__ w,
    const float* __restrict__ bias, float* __restrict__ y)
{
  int idx = blockIdx.x * 256 + threadIdx.x;   // enumerates (b, t, co)
  int co = idx & 63;
  int r  = idx >> 6;
  int t  = r & 32767;
  int b  = r >> 15;
  const float* xb = x + (size_t)b * 65536;
  float acc = bias[co];
  #pragma unroll
  for (int k = 0; k < 4; ++k) {
    int gt = 2 * t - 1 + k;
    float xv = ((unsigned)gt < 65536u) ? xb[gt] : 0.f;
    acc += xv * w[k * 64 + co];
  }
  y[(size_t)idx] = fmaxf(acc, 0.f);
}

// ---------------- conv3: K=3, dil DIL, 64->64, relu, optional +res --------
// Block 256 thr = 4 waves; wave wv owns co0 = wv*16 (wave-uniform);
// lane = t, 2 t per lane (t0+lane, t0+lane+64). grid (T/128, 4).
template <int DIL, bool HAS_RES>
__global__ __launch_bounds__(256, 4) void conv3_kernel(
    const float* __restrict__ x, const float* __restrict__ w,
    const float* __restrict__ bias, const float* res,
    float* y, int T)
{
  constexpr int TT = 128;
  constexpr int XT = TT + 2 * DIL;
  constexpr int XS = XT + 1;                 // odd stride
  __shared__ float xs[64 * XS];
  const int tid  = threadIdx.x;
  const int lane = tid & 63;
  const int b    = blockIdx.y;
  const int t0   = blockIdx.x * TT;
  const int wv   = __builtin_amdgcn_readfirstlane(tid >> 6);
  const int co0  = __builtin_amdgcn_readfirstlane(wv * 16);

  const float* xb = x + (size_t)b * T * 64;
  for (int e = tid; e < 16 * XT; e += 256) { // transpose to [ci][t]
    int tl = e >> 4, cq = (e & 15) * 4;
    int gt = t0 - DIL + tl;
    float4 v = make_float4(0.f, 0.f, 0.f, 0.f);
    if ((unsigned)gt < (unsigned)T) v = *(const float4*)&xb[(size_t)gt * 64 + cq];
    xs[(cq + 0) * XS + tl] = v.x;
    xs[(cq + 1) * XS + tl] = v.y;
    xs[(cq + 2) * XS + tl] = v.z;
    xs[(cq + 3) * XS + tl] = v.w;
  }
  __syncthreads();

  float acc0[16] = {}, acc1[16] = {};
  const float* wb = w + co0;                 // w[k][ci][co0..co0+15]
  for (int ci = 0; ci < 64; ++ci) {
    const float* xr = xs + ci * XS + lane;
    float a0 = xr[0],  a1 = xr[DIL],      a2 = xr[2 * DIL];
    float b0 = xr[64], b1 = xr[64 + DIL], b2 = xr[64 + 2 * DIL];
    const float* w0 = wb + (0 * 64 + ci) * 64;
    const float* w1 = wb + (1 * 64 + ci) * 64;
    const float* w2 = wb + (2 * 64 + ci) * 64;
    #pragma unroll
    for (int j = 0; j < 16; ++j) {
      float c0 = w0[j], c1 = w1[j], c2 = w2[j];
      acc0[j] = fmaf(a0, c0, fmaf(a1, c1, fmaf(a2, c2, acc0[j])));
      acc1[j] = fmaf(b0, c0, fmaf(b1, c1, fmaf(b2, c2, acc1[j])));
    }
  }

  size_t o0 = ((size_t)b * T + t0 + lane) * 64 + co0;
  size_t o1 = o0 + (size_t)64 * 64;
  float r0[16], r1[16];
  #pragma unroll
  for (int j = 0; j < 16; ++j) {
    float bj = bias[co0 + j];
    r0[j] = fmaxf(acc0[j] + bj, 0.f);
    r1[j] = fmaxf(acc1[j] + bj, 0.f);
  }
  if (HAS_RES) {
    #pragma unroll
    for (int q = 0; q < 4; ++q) {
      float4 v0 = *(const float4*)&res[o0 + 4 * q];
      float4 v1 = *(const float4*)&res[o1 + 4 * q];
      r0[4*q+0] += v0.x; r0[4*q+1] += v0.y; r0[4*q+2] += v0.z; r0[4*q+3] += v0.w;
      r1[4*q+0] += v1.x; r1[4*q+1] += v1.y; r1[4*q+2] += v1.z; r1[4*q+3] += v1.w;
    }
  }
  #pragma unroll
  for (int q = 0; q < 4; ++q) {
    *(float4*)&y[o0 + 4 * q] = make_float4(r0[4*q], r0[4*q+1], r0[4*q+2], r0[4*q+3]);
    *(float4*)&y[o1 + 4 * q] = make_float4(r1[4*q], r1[4*q+1], r1[4*q+2], r1[4*q+3]);
  }
}

// ---------------- down2: K=4 stride2, 64->64, relu ------------------------
// Block 4 waves; wave owns co0 = wv*16; lane = out t (64/block). grid (Tout/64, 4).
__global__ __launch_bounds__(256, 4) void down2_kernel(
    const float* __restrict__ x, const float* __restrict__ w,
    const float* __restrict__ bias, float* __restrict__ y, int Tin)
{
  constexpr int XT = 130, XS = 131;
  __shared__ float xs[64 * XS];
  const int tid  = threadIdx.x;
  const int lane = tid & 63;
  const int b    = blockIdx.y;
  const int t0   = blockIdx.x * 64;
  const int Tout = Tin >> 1;
  const int wv   = __builtin_amdgcn_readfirstlane(tid >> 6);
  const int co0  = __builtin_amdgcn_readfirstlane(wv * 16);

  const float* xb = x + (size_t)b * Tin * 64;
  for (int e = tid; e < 16 * XT; e += 256) {
    int tl = e >> 4, cq = (e & 15) * 4;
    int gt = 2 * t0 - 1 + tl;
    float4 v = make_float4(0.f, 0.f, 0.f, 0.f);
    if ((unsigned)gt < (unsigned)Tin) v = *(const float4*)&xb[(size_t)gt * 64 + cq];
    xs[(cq + 0) * XS + tl] = v.x;
    xs[(cq + 1) * XS + tl] = v.y;
    xs[(cq + 2) * XS + tl] = v.z;
    xs[(cq + 3) * XS + tl] = v.w;
  }
  __syncthreads();

  float acc[16] = {};
  const float* wb = w + co0;
  for (int ci = 0; ci < 64; ++ci) {
    const float* xr = xs + ci * XS + 2 * lane;
    float a0 = xr[0], a1 = xr[1], a2 = xr[2], a3 = xr[3];
    const float* w0 = wb + (0 * 64 + ci) * 64;
    const float* w1 = wb + (1 * 64 + ci) * 64;
    const float* w2 = wb + (2 * 64 + ci) * 64;
    const float* w3 = wb + (3 * 64 + ci) * 64;
    #pragma unroll
    for (int j = 0; j < 16; ++j)
      acc[j] = fmaf(a0, w0[j], fmaf(a1, w1[j], fmaf(a2, w2[j], fmaf(a3, w3[j], acc[j]))));
  }

  size_t o = ((size_t)b * Tout + t0 + lane) * 64 + co0;
  #pragma unroll
  for (int q = 0; q < 4; ++q) {
    float4 rr;
    rr.x = fmaxf(acc[4*q+0] + bias[co0 + 4*q+0], 0.f);
    rr.y = fmaxf(acc[4*q+1] + bias[co0 + 4*q+1], 0.f);
    rr.z = fmaxf(acc[4*q+2] + bias[co0 + 4*q+2], 0.f);
    rr.w = fmaxf(acc[4*q+3] + bias[co0 + 4*q+3], 0.f);
    *(float4*)&y[o + 4 * q] = rr;
  }
}

// ---------------- up: conv_transpose K=4 stride2, 64->64, relu ------------
// y[2u] = relu(b + w0^T x[u-1] + w2^T x[u]); y[2u+1] = relu(b + w1^T x[u] + w3^T x[u+1])
// Block 4 waves; wave owns co0 = wv*16; lane = u (64 u -> 128 t / block).
// grid (Tout/128, 4).
__global__ __launch_bounds__(256, 4) void up_kernel(
    const float* __restrict__ x, const float* __restrict__ w,
    const float* __restrict__ bias, float* __restrict__ y, int Tin)
{
  constexpr int XT = 66, XS = 67;
  __shared__ float xs[64 * XS];
  const int tid  = threadIdx.x;
  const int lane = tid & 63;
  const int b    = blockIdx.y;
  const int u0   = blockIdx.x * 64;
  const int Tout = Tin << 1;
  const int wv   = __builtin_amdgcn_readfirstlane(tid >> 6);
  const int co0  = __builtin_amdgcn_readfirstlane(wv * 16);

  const float* xb = x + (size_t)b * Tin * 64;
  for (int e = tid; e < 16 * XT; e += 256) {
    int ul = e >> 4, cq = (e & 15) * 4;
    int gu = u0 - 1 + ul;
    float4 v = make_float4(0.f, 0.f, 0.f, 0.f);
    if ((unsigned)gu < (unsigned)Tin) v = *(const float4*)&xb[(size_t)gu * 64 + cq];
    xs[(cq + 0) * XS + ul] = v.x;
    xs[(cq + 1) * XS + ul] = v.y;
    xs[(cq + 2) * XS + ul] = v.z;
    xs[(cq + 3) * XS + ul] = v.w;
  }
  __syncthreads();

  float acce[16] = {}, acco[16] = {};
  const float* wb = w + co0;
  for (int ci = 0; ci < 64; ++ci) {
    const float* xr = xs + ci * XS + lane;
    float a0 = xr[0], a1 = xr[1], a2 = xr[2];  // x[u-1], x[u], x[u+1]
    const float* w0 = wb + (0 * 64 + ci) * 64;
    const float* w1 = wb + (1 * 64 + ci) * 64;
    const float* w2 = wb + (2 * 64 + ci) * 64;
    const float* w3 = wb + (3 * 64 + ci) * 64;
    #pragma unroll
    for (int j = 0; j < 16; ++j) {
      acce[j] = fmaf(a0, w0[j], fmaf(a1, w2[j], acce[j]));
      acco[j] = fmaf(a1, w1[j], fmaf(a2, w3[j], acco[j]));
    }
  }

  size_t oe = ((size_t)b * Tout + 2 * (u0 + lane)) * 64 + co0;
  size_t oo = oe + 64;
  #pragma unroll
  for (int q = 0; q < 4; ++q) {
    float4 re, ro;
    re.x = fmaxf(acce[4*q+0] + bias[co0 + 4*q+0], 0.f);
    re.y = fmaxf(acce[4*q+1] + bias[co0 + 4*q+1], 0.f);
    re.z = fmaxf(acce[4*q+2] + bias[co0 + 4*q+2], 0.f);
    re.w = fmaxf(acce[4*q+3] + bias[co0 + 4*q+3], 0.f);
    ro.x = fmaxf(acco[4*q+0] + bias[co0 + 4*q+0], 0.f);
    ro.y = fmaxf(acco[4*q+1] + bias[co0 + 4*q+1], 0.f);
    ro.z = fmaxf(acco[4*q+2] + bias[co0 + 4*q+2], 0.f);
    ro.w = fmaxf(acco[4*q+3] + bias[co0 + 4*q+3], 0.f);
    *(float4*)&y[oe + 4 * q] = re;
    *(float4*)&y[oo + 4 * q] = ro;
  }
}

// ---------------- proj: K=3 dil1, 64->1, linear ---------------------------
__global__ __launch_bounds__(256) void proj_kernel(
    const float* __restrict__ x, const float* __restrict__ w,
    const float* __restrict__ bias, float* __restrict__ out)
{
  const int lane = threadIdx.x & 63;
  const int wid  = (blockIdx.x * 256 + threadIdx.x) >> 6;  // 4096 waves
  const float w0 = w[lane], w1 = w[64 + lane], w2 = w[128 + lane];
  const float bb = bias[0];
  size_t base = (size_t)wid * 64;
  for (int i = 0; i < 64; ++i) {
    size_t tau = base + i;
    int b = (int)(tau >> 16);
    int t = (int)(tau & 65535);
    const float* xb = x + ((size_t)b * 65536) * 64;
    float pm = (t > 0)     ? xb[(size_t)(t - 1) * 64 + lane] : 0.f;
    float pc =               xb[(size_t)t * 64 + lane];
    float pp = (t < 65535) ? xb[(size_t)(t + 1) * 64 + lane] : 0.f;
    float s = pm * w0 + pc * w1 + pp * w2;
    #pragma unroll
    for (int off = 32; off; off >>= 1) s += __shfl_down(s, off);
    if (lane == 0) out[tau] = s + bb;
  }
}

// ---------------- nz: per-token sum of squares ----------------------------
__global__ __launch_bounds__(256) void nz_kernel(
    const float* __restrict__ ze, float* __restrict__ nz)
{
  int lane = threadIdx.x & 63;
  int tok  = (blockIdx.x * 256 + threadIdx.x) >> 6;
  float v = ze[(size_t)tok * 64 + lane];
  float s = v * v;
  #pragma unroll
  for (int off = 32; off; off >>= 1) s += __shfl_down(s, off);
  if (lane == 0) nz[tok] = s;
}

// ---------------- vq_dots: 1 cb row/thread, 2 tokens/iter, 4 FMA chains ---
#define VQA_TOKS 32
__global__ __launch_bounds__(256) void vq_dots_kernel(
    const float* __restrict__ ze, const float* __restrict__ cb,
    const float* __restrict__ nzbuf, float* __restrict__ sim_out,
    float2* __restrict__ pmin)
{
  __shared__ float zs[VQA_TOKS * 64];        // 8 KB
  const int tid = threadIdx.x;
  {
    const float4* src = (const float4*)(ze + (size_t)blockIdx.x * VQA_TOKS * 64);
    float4* dst = (float4*)zs;
    dst[tid]       = src[tid];
    dst[tid + 256] = src[tid + 256];
  }
  const int c = blockIdx.y * 256 + tid;
  float r[64];
  #pragma unroll
  for (int q = 0; q < 16; ++q) {
    float4 a = ((const float4*)cb)[(size_t)c * 16 + q];
    r[4*q] = a.x; r[4*q+1] = a.y; r[4*q+2] = a.z; r[4*q+3] = a.w;
  }
  float ne = 0.f;
  #pragma unroll
  for (int d = 0; d < 64; ++d) ne += r[d] * r[d];
  const float rsne = 1.f / sqrtf(ne);
  const int wvid = tid >> 6;
  __syncthreads();

  for (int it = 0; it < VQA_TOKS; it += 2) {
    const int ta = blockIdx.x * VQA_TOKS + it;
    const float4* za = (const float4*)(zs + it * 64);
    const float4* zb = za + 16;
    float da0 = 0.f, da1 = 0.f, db0 = 0.f, db1 = 0.f;
    #pragma unroll
    for (int q = 0; q < 16; q += 2) {
      float4 va0 = za[q], va1 = za[q + 1];
      float4 vb0 = zb[q], vb1 = zb[q + 1];
      da0 = fmaf(va0.x, r[4*q],   fmaf(va0.y, r[4*q+1], fmaf(va0.z, r[4*q+2], fmaf(va0.w, r[4*q+3], da0))));
      da1 = fmaf(va1.x, r[4*q+4], fmaf(va1.y, r[4*q+5], fmaf(va1.z, r[4*q+6], fmaf(va1.w, r[4*q+7], da1))));
      db0 = fmaf(vb0.x, r[4*q],   fmaf(vb0.y, r[4*q+1], fmaf(vb0.z, r[4*q+2], fmaf(vb0.w, r[4*q+3], db0))));
      db1 = fmaf(vb1.x, r[4*q+4], fmaf(vb1.y, r[4*q+5], fmaf(vb1.z, r[4*q+6], fmaf(vb1.w, r[4*q+7], db1))));
    }
    float dota = da0 + da1, dotb = db0 + db1;
    float nza = nzbuf[ta], nzb = nzbuf[ta + 1];
    sim_out[(size_t)ta * 512 + c]       = dota * (1.f / sqrtf(nza)) * rsne;
    sim_out[(size_t)(ta + 1) * 512 + c] = dotb * (1.f / sqrtf(nzb)) * rsne;
    float dista = (-2.f * dota + nza) + ne;
    float distb = (-2.f * dotb + nzb) + ne;

    float mda = dista; int mia = c;
    float mdb = distb; int mib = c;
    #pragma unroll
    for (int off = 32; off; off >>= 1) {
      float oda = __shfl_down(mda, off);
      int   oia = __shfl_down(mia, off);
      float odb = __shfl_down(mdb, off);
      int   oib = __shfl_down(mib, off);
      if (oda < mda || (oda == mda && oia < mia)) { mda = oda; mia = oia; }
      if (odb < mdb || (odb == mdb && oib < mib)) { mdb = odb; mib = oib; }
    }
    if ((tid & 63) == 0) {
      pmin[ta * 8 + blockIdx.y * 4 + wvid]       = make_float2(mda, (float)mia);
      pmin[(ta + 1) * 8 + blockIdx.y * 4 + wvid] = make_float2(mdb, (float)mib);
    }
  }
}

// ---------------- vq_finish: cross-partial argmin, z_q, ids, loss ---------
__global__ __launch_bounds__(256) void vq_finish_kernel(
    const float* __restrict__ ze, const float* __restrict__ cb,
    const float2* __restrict__ pmin, float* __restrict__ zq,
    float* __restrict__ ids_out, float* __restrict__ blocksum)
{
  const int tid = threadIdx.x;
  const int lane = tid & 63, wvid = tid >> 6;
  float lloss = 0.f;
  for (int it = 0; it < 16; ++it) {
    const int tok = blockIdx.x * 64 + wvid * 16 + it;
    float bd = 1e30f; int bi = 0;
    #pragma unroll
    for (int p = 0; p < 8; ++p) {
      float2 pr = pmin[tok * 8 + p];
      float d = pr.x; int i = (int)pr.y;
      if (d < bd || (d == bd && i < bi)) { bd = d; bi = i; }
    }
    float zev = ze[(size_t)tok * 64 + lane];
    float cv  = cb[(size_t)bi * 64 + lane];
    float df = zev - cv;
    float s = df * df;
    #pragma unroll
    for (int off = 32; off; off >>= 1) s += __shfl_down(s, off);
    zq[(size_t)tok * 64 + lane] = cv;
    if (lane == 0) { ids_out[tok] = (float)bi; lloss += sqrtf(s); }
  }
  __shared__ float ls[4];
  if (lane == 0) ls[wvid] = lloss;
  __syncthreads();
  if (tid == 0) blocksum[blockIdx.x] = ls[0] + ls[1] + ls[2] + ls[3];
}

__global__ void loss_fin_kernel(const float* __restrict__ blocksum,
                                float* __restrict__ out)
{
  const int lane = threadIdx.x;  // 64 threads
  float s = 0.f;
  for (int i = lane; i < 512; i += 64) s += blocksum[i];
  #pragma unroll
  for (int off = 32; off; off >>= 1) s += __shfl_down(s, off);
  if (lane == 0) out[0] = 1.25f * s / 32768.f;
}

// ---------------------------------------------------------------------------
extern "C" void kernel_launch(void* const* d_in, const int* in_sizes, int n_in,
                              void* d_out, int out_size, void* d_ws, size_t ws_size,
                              hipStream_t stream)
{
  const float* x       = (const float*)d_in[0];
  const float* w_down0 = (const float*)d_in[1];
  const float* b_down0 = (const float*)d_in[2];
  const float* w_down  = (const float*)d_in[3];
  const float* b_down  = (const float*)d_in[4];
  const float* w_res_e = (const float*)d_in[5];
  const float* b_res_e = (const float*)d_in[6];
  const float* cb      = (const float*)d_in[7];
  const float* w_res_d = (const float*)d_in[8];
  const float* b_res_d = (const float*)d_in[9];
  const float* w_up    = (const float*)d_in[10];
  const float* b_up    = (const float*)d_in[11];
  const float* w_proj  = (const float*)d_in[12];
  const float* b_proj  = (const float*)d_in[13];

  float* out = (float*)d_out;
  const size_t BUF = (size_t)4 * 65536 * 64;
  float*  bufA     = (float*)d_ws;
  float*  bufB     = bufA + BUF;
  float*  nzbuf    = bufB + BUF;
  float2* pmin     = (float2*)(nzbuf + 32768);
  float*  blocksum = (float*)(pmin + 32768 * 8);

  float* h = bufA;
  float* tmp = bufB;

  // ---- encoder ----
  down0_kernel<<<32768, 256, 0, stream>>>(x, w_down0, b_down0, h);
  int T = 32768;
  for (int blk = 0; blk < 3; ++blk) {
    if (blk > 0) {
      down2_kernel<<<dim3(T / 2 / 64, 4), 256, 0, stream>>>(
          h, w_down + (size_t)(blk - 1) * 4 * 64 * 64, b_down + (blk - 1) * 64, tmp, T);
      T >>= 1;
      float* s = h; h = tmp; tmp = s;
    }
    for (int r = 0; r < 4; ++r) {
      const float* w0p = w_res_e + (((size_t)blk * 4 + r) * 2 + 0) * 3 * 64 * 64;
      const float* w1p = w_res_e + (((size_t)blk * 4 + r) * 2 + 1) * 3 * 64 * 64;
      const float* b0p = b_res_e + (((size_t)blk * 4 + r) * 2 + 0) * 64;
      const float* b1p = b_res_e + (((size_t)blk * 4 + r) * 2 + 1) * 64;
      conv3_kernel<3, false><<<dim3(T / 128, 4), 256, 0, stream>>>(h, w0p, b0p, nullptr, tmp, T);
      conv3_kernel<1, true ><<<dim3(T / 128, 4), 256, 0, stream>>>(tmp, w1p, b1p, h, h, T);
    }
  }

  // ---- VQ (T == 8192, z_e in h; 32768 tokens) ----
  nz_kernel<<<8192, 256, 0, stream>>>(h, nzbuf);
  vq_dots_kernel<<<dim3(32768 / VQA_TOKS, 2), 256, 0, stream>>>(h, cb, nzbuf, out + OFF_SIM, pmin);
  vq_finish_kernel<<<512, 256, 0, stream>>>(h, cb, pmin, tmp, out + OFF_IDS, blocksum);
  loss_fin_kernel<<<1, 64, 0, stream>>>(blocksum, out + OFF_LOSS);
  { float* s = h; h = tmp; tmp = s; }  // h = z_q

  // ---- decoder ----
  for (int blk = 0; blk < 3; ++blk) {
    for (int r = 0; r < 4; ++r) {
      const float* w0p = w_res_d + (((size_t)blk * 4 + r) * 2 + 0) * 3 * 64 * 64;
      const float* w1p = w_res_d + (((size_t)blk * 4 + r) * 2 + 1) * 3 * 64 * 64;
      const float* b0p = b_res_d + (((size_t)blk * 4 + r) * 2 + 0) * 64;
      const float* b1p = b_res_d + (((size_t)blk * 4 + r) * 2 + 1) * 64;
      conv3_kernel<1, false><<<dim3(T / 128, 4), 256, 0, stream>>>(h, w0p, b0p, nullptr, tmp, T);
      conv3_kernel<3, true ><<<dim3(T / 128, 4), 256, 0, stream>>>(tmp, w1p, b1p, h, h, T);
    }
    up_kernel<<<dim3(2 * T / 128, 4), 256, 0, stream>>>(
        h, w_up + (size_t)blk * 4 * 64 * 64, b_up + blk * 64, tmp, T);
    T <<= 1;
    float* s = h; h = tmp; tmp = s;
  }

  // ---- final projection (T == 65536) ----
  proj_kernel<<<1024, 256, 0, stream>>>(h, w_proj, b_proj, out);
}

// Round 6
// 1787.001 us; speedup vs baseline: 1.2879x; 1.2879x over previous
//
#include <hip/hip_runtime.h>
#include <cstdint>

// ---------------------------------------------------------------------------
// JukeboxAutoEncoder fp32, round 6.
// convs: 512-thr blocks (8 waves x 8 wave-uniform co), xs staged once,
//        34.6KB LDS -> 4 blocks/CU -> 32 waves/CU. Weights via s_load.
// vq_dots: z_e read through wave-uniform pointer -> scalar s_loads (no LDS
//        staging, LDS pipe freed for argmin bpermutes); cb rows in VGPRs.
// Output layout (flat f32): x_hat[262144] | loss_vq[1] | ids[32768] | sim[16777216]
// ---------------------------------------------------------------------------

#define OFF_LOSS 262144
#define OFF_IDS  262145
#define OFF_SIM  294913

// ---------------- down0: (B,65536,1) -> (B,32768,64), K=4 stride2, relu ----
__global__ __launch_bounds__(256) void down0_kernel(
    const float* __restrict__ x, const float* __restrict__ w,
    const float* __restrict__ bias, float* __restrict__ y)
{
  int idx = blockIdx.x * 256 + threadIdx.x;   // enumerates (b, t, co)
  int co = idx & 63;
  int r  = idx >> 6;
  int t  = r & 32767;
  int b  = r >> 15;
  const float* xb = x + (size_t)b * 65536;
  float acc = bias[co];
  #pragma unroll
  for (int k = 0; k < 4; ++k) {
    int gt = 2 * t - 1 + k;
    float xv = ((unsigned)gt < 65536u) ? xb[gt] : 0.f;
    acc += xv * w[k * 64 + co];
  }
  y[(size_t)idx] = fmaxf(acc, 0.f);
}

// ---------------- conv3: K=3, dil DIL, 64->64, relu, optional +res --------
// 512 thr = 8 waves; wave wv owns co0 = wv*8 (wave-uniform -> s_load weights);
// lane = t, 2 t per lane (t0+lane, t0+lane+64). grid (T/128, 4).
template <int DIL, bool HAS_RES>
__global__ __launch_bounds__(512, 8) void conv3_kernel(
    const float* __restrict__ x, const float* __restrict__ w,
    const float* __restrict__ bias, const float* res,
    float* y, int T)
{
  constexpr int TT = 128;
  constexpr int XT = TT + 2 * DIL;
  constexpr int XS = XT + 1;                 // odd stride
  __shared__ float xs[64 * XS];
  const int tid  = threadIdx.x;
  const int lane = tid & 63;
  const int b    = blockIdx.y;
  const int t0   = blockIdx.x * TT;
  const int wv   = __builtin_amdgcn_readfirstlane(tid >> 6);
  const int co0  = __builtin_amdgcn_readfirstlane(wv * 8);

  const float* xb = x + (size_t)b * T * 64;
  for (int e = tid; e < 16 * XT; e += 512) { // transpose to [ci][t]
    int tl = e >> 4, cq = (e & 15) * 4;
    int gt = t0 - DIL + tl;
    float4 v = make_float4(0.f, 0.f, 0.f, 0.f);
    if ((unsigned)gt < (unsigned)T) v = *(const float4*)&xb[(size_t)gt * 64 + cq];
    xs[(cq + 0) * XS + tl] = v.x;
    xs[(cq + 1) * XS + tl] = v.y;
    xs[(cq + 2) * XS + tl] = v.z;
    xs[(cq + 3) * XS + tl] = v.w;
  }
  __syncthreads();

  float acc0[8] = {}, acc1[8] = {};
  const float* wb = w + co0;                 // w[k][ci][co0..co0+7]
  for (int ci = 0; ci < 64; ++ci) {
    const float* xr = xs + ci * XS + lane;
    float a0 = xr[0],  a1 = xr[DIL],      a2 = xr[2 * DIL];
    float b0 = xr[64], b1 = xr[64 + DIL], b2 = xr[64 + 2 * DIL];
    const float* w0 = wb + (0 * 64 + ci) * 64;
    const float* w1 = wb + (1 * 64 + ci) * 64;
    const float* w2 = wb + (2 * 64 + ci) * 64;
    #pragma unroll
    for (int j = 0; j < 8; ++j) {
      float c0 = w0[j], c1 = w1[j], c2 = w2[j];
      acc0[j] = fmaf(a0, c0, fmaf(a1, c1, fmaf(a2, c2, acc0[j])));
      acc1[j] = fmaf(b0, c0, fmaf(b1, c1, fmaf(b2, c2, acc1[j])));
    }
  }

  size_t o0 = ((size_t)b * T + t0 + lane) * 64 + co0;
  size_t o1 = o0 + (size_t)64 * 64;
  float r0[8], r1[8];
  #pragma unroll
  for (int j = 0; j < 8; ++j) {
    float bj = bias[co0 + j];
    r0[j] = fmaxf(acc0[j] + bj, 0.f);
    r1[j] = fmaxf(acc1[j] + bj, 0.f);
  }
  if (HAS_RES) {
    #pragma unroll
    for (int q = 0; q < 2; ++q) {
      float4 v0 = *(const float4*)&res[o0 + 4 * q];
      float4 v1 = *(const float4*)&res[o1 + 4 * q];
      r0[4*q+0] += v0.x; r0[4*q+1] += v0.y; r0[4*q+2] += v0.z; r0[4*q+3] += v0.w;
      r1[4*q+0] += v1.x; r1[4*q+1] += v1.y; r1[4*q+2] += v1.z; r1[4*q+3] += v1.w;
    }
  }
  #pragma unroll
  for (int q = 0; q < 2; ++q) {
    *(float4*)&y[o0 + 4 * q] = make_float4(r0[4*q], r0[4*q+1], r0[4*q+2], r0[4*q+3]);
    *(float4*)&y[o1 + 4 * q] = make_float4(r1[4*q], r1[4*q+1], r1[4*q+2], r1[4*q+3]);
  }
}

// ---------------- down2: K=4 stride2, 64->64, relu ------------------------
// 512 thr = 8 waves; wave owns co0 = wv*8; lane = out t (64/block).
// grid (Tout/64, 4).
__global__ __launch_bounds__(512, 8) void down2_kernel(
    const float* __restrict__ x, const float* __restrict__ w,
    const float* __restrict__ bias, float* __restrict__ y, int Tin)
{
  constexpr int XT = 130, XS = 131;
  __shared__ float xs[64 * XS];
  const int tid  = threadIdx.x;
  const int lane = tid & 63;
  const int b    = blockIdx.y;
  const int t0   = blockIdx.x * 64;
  const int Tout = Tin >> 1;
  const int wv   = __builtin_amdgcn_readfirstlane(tid >> 6);
  const int co0  = __builtin_amdgcn_readfirstlane(wv * 8);

  const float* xb = x + (size_t)b * Tin * 64;
  for (int e = tid; e < 16 * XT; e += 512) {
    int tl = e >> 4, cq = (e & 15) * 4;
    int gt = 2 * t0 - 1 + tl;
    float4 v = make_float4(0.f, 0.f, 0.f, 0.f);
    if ((unsigned)gt < (unsigned)Tin) v = *(const float4*)&xb[(size_t)gt * 64 + cq];
    xs[(cq + 0) * XS + tl] = v.x;
    xs[(cq + 1) * XS + tl] = v.y;
    xs[(cq + 2) * XS + tl] = v.z;
    xs[(cq + 3) * XS + tl] = v.w;
  }
  __syncthreads();

  float acc[8] = {};
  const float* wb = w + co0;
  for (int ci = 0; ci < 64; ++ci) {
    const float* xr = xs + ci * XS + 2 * lane;
    float a0 = xr[0], a1 = xr[1], a2 = xr[2], a3 = xr[3];
    const float* w0 = wb + (0 * 64 + ci) * 64;
    const float* w1 = wb + (1 * 64 + ci) * 64;
    const float* w2 = wb + (2 * 64 + ci) * 64;
    const float* w3 = wb + (3 * 64 + ci) * 64;
    #pragma unroll
    for (int j = 0; j < 8; ++j)
      acc[j] = fmaf(a0, w0[j], fmaf(a1, w1[j], fmaf(a2, w2[j], fmaf(a3, w3[j], acc[j]))));
  }

  size_t o = ((size_t)b * Tout + t0 + lane) * 64 + co0;
  #pragma unroll
  for (int q = 0; q < 2; ++q) {
    float4 rr;
    rr.x = fmaxf(acc[4*q+0] + bias[co0 + 4*q+0], 0.f);
    rr.y = fmaxf(acc[4*q+1] + bias[co0 + 4*q+1], 0.f);
    rr.z = fmaxf(acc[4*q+2] + bias[co0 + 4*q+2], 0.f);
    rr.w = fmaxf(acc[4*q+3] + bias[co0 + 4*q+3], 0.f);
    *(float4*)&y[o + 4 * q] = rr;
  }
}

// ---------------- up: conv_transpose K=4 stride2, 64->64, relu ------------
// y[2u] = relu(b + w0^T x[u-1] + w2^T x[u]); y[2u+1] = relu(b + w1^T x[u] + w3^T x[u+1])
// 512 thr = 8 waves; wave owns co0 = wv*8; lane = u (64 u = 128 out t).
// grid (Tout/128, 4).
__global__ __launch_bounds__(512, 8) void up_kernel(
    const float* __restrict__ x, const float* __restrict__ w,
    const float* __restrict__ bias, float* __restrict__ y, int Tin)
{
  constexpr int XT = 66, XS = 67;
  __shared__ float xs[64 * XS];
  const int tid  = threadIdx.x;
  const int lane = tid & 63;
  const int b    = blockIdx.y;
  const int u0   = blockIdx.x * 64;
  const int Tout = Tin << 1;
  const int wv   = __builtin_amdgcn_readfirstlane(tid >> 6);
  const int co0  = __builtin_amdgcn_readfirstlane(wv * 8);

  const float* xb = x + (size_t)b * Tin * 64;
  for (int e = tid; e < 16 * XT; e += 512) {
    int ul = e >> 4, cq = (e & 15) * 4;
    int gu = u0 - 1 + ul;
    float4 v = make_float4(0.f, 0.f, 0.f, 0.f);
    if ((unsigned)gu < (unsigned)Tin) v = *(const float4*)&xb[(size_t)gu * 64 + cq];
    xs[(cq + 0) * XS + ul] = v.x;
    xs[(cq + 1) * XS + ul] = v.y;
    xs[(cq + 2) * XS + ul] = v.z;
    xs[(cq + 3) * XS + ul] = v.w;
  }
  __syncthreads();

  float acce[8] = {}, acco[8] = {};
  const float* wb = w + co0;
  for (int ci = 0; ci < 64; ++ci) {
    const float* xr = xs + ci * XS + lane;
    float a0 = xr[0], a1 = xr[1], a2 = xr[2];  // x[u-1], x[u], x[u+1]
    const float* w0 = wb + (0 * 64 + ci) * 64;
    const float* w1 = wb + (1 * 64 + ci) * 64;
    const float* w2 = wb + (2 * 64 + ci) * 64;
    const float* w3 = wb + (3 * 64 + ci) * 64;
    #pragma unroll
    for (int j = 0; j < 8; ++j) {
      acce[j] = fmaf(a0, w0[j], fmaf(a1, w2[j], acce[j]));
      acco[j] = fmaf(a1, w1[j], fmaf(a2, w3[j], acco[j]));
    }
  }

  size_t oe = ((size_t)b * Tout + 2 * (u0 + lane)) * 64 + co0;
  size_t oo = oe + 64;
  #pragma unroll
  for (int q = 0; q < 2; ++q) {
    float4 re, ro;
    re.x = fmaxf(acce[4*q+0] + bias[co0 + 4*q+0], 0.f);
    re.y = fmaxf(acce[4*q+1] + bias[co0 + 4*q+1], 0.f);
    re.z = fmaxf(acce[4*q+2] + bias[co0 + 4*q+2], 0.f);
    re.w = fmaxf(acce[4*q+3] + bias[co0 + 4*q+3], 0.f);
    ro.x = fmaxf(acco[4*q+0] + bias[co0 + 4*q+0], 0.f);
    ro.y = fmaxf(acco[4*q+1] + bias[co0 + 4*q+1], 0.f);
    ro.z = fmaxf(acco[4*q+2] + bias[co0 + 4*q+2], 0.f);
    ro.w = fmaxf(acco[4*q+3] + bias[co0 + 4*q+3], 0.f);
    *(float4*)&y[oe + 4 * q] = re;
    *(float4*)&y[oo + 4 * q] = ro;
  }
}

// ---------------- proj: K=3 dil1, 64->1, linear ---------------------------
__global__ __launch_bounds__(256) void proj_kernel(
    const float* __restrict__ x, const float* __restrict__ w,
    const float* __restrict__ bias, float* __restrict__ out)
{
  const int lane = threadIdx.x & 63;
  const int wid  = (blockIdx.x * 256 + threadIdx.x) >> 6;  // 4096 waves
  const float w0 = w[lane], w1 = w[64 + lane], w2 = w[128 + lane];
  const float bb = bias[0];
  size_t base = (size_t)wid * 64;
  for (int i = 0; i < 64; ++i) {
    size_t tau = base + i;
    int b = (int)(tau >> 16);
    int t = (int)(tau & 65535);
    const float* xb = x + ((size_t)b * 65536) * 64;
    float pm = (t > 0)     ? xb[(size_t)(t - 1) * 64 + lane] : 0.f;
    float pc =               xb[(size_t)t * 64 + lane];
    float pp = (t < 65535) ? xb[(size_t)(t + 1) * 64 + lane] : 0.f;
    float s = pm * w0 + pc * w1 + pp * w2;
    #pragma unroll
    for (int off = 32; off; off >>= 1) s += __shfl_down(s, off);
    if (lane == 0) out[tau] = s + bb;
  }
}

// ---------------- nz: per-token sum of squares ----------------------------
__global__ __launch_bounds__(256) void nz_kernel(
    const float* __restrict__ ze, float* __restrict__ nz)
{
  int lane = threadIdx.x & 63;
  int tok  = (blockIdx.x * 256 + threadIdx.x) >> 6;
  float v = ze[(size_t)tok * 64 + lane];
  float s = v * v;
  #pragma unroll
  for (int off = 32; off; off >>= 1) s += __shfl_down(s, off);
  if (lane == 0) nz[tok] = s;
}

// ---------------- vq_dots: cb row per thread, z via wave-uniform s_load ---
#define VQA_TOKS 32
__global__ __launch_bounds__(256) void vq_dots_kernel(
    const float* __restrict__ ze, const float* __restrict__ cb,
    const float* __restrict__ nzbuf, float* __restrict__ sim_out,
    float2* __restrict__ pmin)
{
  const int tid = threadIdx.x;
  const int c = blockIdx.y * 256 + tid;
  float r[64];
  #pragma unroll
  for (int q = 0; q < 16; ++q) {
    float4 a = ((const float4*)cb)[(size_t)c * 16 + q];
    r[4*q] = a.x; r[4*q+1] = a.y; r[4*q+2] = a.z; r[4*q+3] = a.w;
  }
  float ne = 0.f;
  #pragma unroll
  for (int d = 0; d < 64; ++d) ne += r[d] * r[d];
  const float rsne = 1.f / sqrtf(ne);
  const int wvid = tid >> 6;

  for (int it = 0; it < VQA_TOKS; ++it) {
    const int tok = blockIdx.x * VQA_TOKS + it;
    const float* zt = ze + (size_t)tok * 64;   // wave-uniform -> s_load
    float d0 = 0.f, d1 = 0.f;
    #pragma unroll
    for (int d = 0; d < 64; d += 8) {
      d0 = fmaf(zt[d+0], r[d+0], fmaf(zt[d+1], r[d+1], fmaf(zt[d+2], r[d+2], fmaf(zt[d+3], r[d+3], d0))));
      d1 = fmaf(zt[d+4], r[d+4], fmaf(zt[d+5], r[d+5], fmaf(zt[d+6], r[d+6], fmaf(zt[d+7], r[d+7], d1))));
    }
    float dot = d0 + d1;
    const float nzv = nzbuf[tok];
    float dist = (-2.f * dot + nzv) + ne;
    sim_out[(size_t)tok * 512 + c] = dot * (1.f / sqrtf(nzv)) * rsne;

    float md = dist; int mi = c;
    #pragma unroll
    for (int off = 32; off; off >>= 1) {
      float od = __shfl_down(md, off);
      int   oi = __shfl_down(mi, off);
      if (od < md || (od == md && oi < mi)) { md = od; mi = oi; }
    }
    if ((tid & 63) == 0) pmin[tok * 8 + blockIdx.y * 4 + wvid] = make_float2(md, (float)mi);
  }
}

// ---------------- vq_finish: cross-partial argmin, z_q, ids, loss ---------
__global__ __launch_bounds__(256) void vq_finish_kernel(
    const float* __restrict__ ze, const float* __restrict__ cb,
    const float2* __restrict__ pmin, float* __restrict__ zq,
    float* __restrict__ ids_out, float* __restrict__ blocksum)
{
  const int tid = threadIdx.x;
  const int lane = tid & 63, wvid = tid >> 6;
  float lloss = 0.f;
  for (int it = 0; it < 16; ++it) {
    const int tok = blockIdx.x * 64 + wvid * 16 + it;
    float bd = 1e30f; int bi = 0;
    #pragma unroll
    for (int p = 0; p < 8; ++p) {
      float2 pr = pmin[tok * 8 + p];
      float d = pr.x; int i = (int)pr.y;
      if (d < bd || (d == bd && i < bi)) { bd = d; bi = i; }
    }
    float zev = ze[(size_t)tok * 64 + lane];
    float cv  = cb[(size_t)bi * 64 + lane];
    float df = zev - cv;
    float s = df * df;
    #pragma unroll
    for (int off = 32; off; off >>= 1) s += __shfl_down(s, off);
    zq[(size_t)tok * 64 + lane] = cv;
    if (lane == 0) { ids_out[tok] = (float)bi; lloss += sqrtf(s); }
  }
  __shared__ float ls[4];
  if (lane == 0) ls[wvid] = lloss;
  __syncthreads();
  if (tid == 0) blocksum[blockIdx.x] = ls[0] + ls[1] + ls[2] + ls[3];
}

__global__ void loss_fin_kernel(const float* __restrict__ blocksum,
                                float* __restrict__ out)
{
  const int lane = threadIdx.x;  // 64 threads
  float s = 0.f;
  for (int i = lane; i < 512; i += 64) s += blocksum[i];
  #pragma unroll
  for (int off = 32; off; off >>= 1) s += __shfl_down(s, off);
  if (lane == 0) out[0] = 1.25f * s / 32768.f;
}

// ---------------------------------------------------------------------------
extern "C" void kernel_launch(void* const* d_in, const int* in_sizes, int n_in,
                              void* d_out, int out_size, void* d_ws, size_t ws_size,
                              hipStream_t stream)
{
  const float* x       = (const float*)d_in[0];
  const float* w_down0 = (const float*)d_in[1];
  const float* b_down0 = (const float*)d_in[2];
  const float* w_down  = (const float*)d_in[3];
  const float* b_down  = (const float*)d_in[4];
  const float* w_res_e = (const float*)d_in[5];
  const float* b_res_e = (const float*)d_in[6];
  const float* cb      = (const float*)d_in[7];
  const float* w_res_d = (const float*)d_in[8];
  const float* b_res_d = (const float*)d_in[9];
  const float* w_up    = (const float*)d_in[10];
  const float* b_up    = (const float*)d_in[11];
  const float* w_proj  = (const float*)d_in[12];
  const float* b_proj  = (const float*)d_in[13];

  float* out = (float*)d_out;
  const size_t BUF = (size_t)4 * 65536 * 64;
  float*  bufA     = (float*)d_ws;
  float*  bufB     = bufA + BUF;
  float*  nzbuf    = bufB + BUF;
  float2* pmin     = (float2*)(nzbuf + 32768);
  float*  blocksum = (float*)(pmin + 32768 * 8);

  float* h = bufA;
  float* tmp = bufB;

  // ---- encoder ----
  down0_kernel<<<32768, 256, 0, stream>>>(x, w_down0, b_down0, h);
  int T = 32768;
  for (int blk = 0; blk < 3; ++blk) {
    if (blk > 0) {
      down2_kernel<<<dim3(T / 2 / 64, 4), 512, 0, stream>>>(
          h, w_down + (size_t)(blk - 1) * 4 * 64 * 64, b_down + (blk - 1) * 64, tmp, T);
      T >>= 1;
      float* s = h; h = tmp; tmp = s;
    }
    for (int r = 0; r < 4; ++r) {
      const float* w0p = w_res_e + (((size_t)blk * 4 + r) * 2 + 0) * 3 * 64 * 64;
      const float* w1p = w_res_e + (((size_t)blk * 4 + r) * 2 + 1) * 3 * 64 * 64;
      const float* b0p = b_res_e + (((size_t)blk * 4 + r) * 2 + 0) * 64;
      const float* b1p = b_res_e + (((size_t)blk * 4 + r) * 2 + 1) * 64;
      conv3_kernel<3, false><<<dim3(T / 128, 4), 512, 0, stream>>>(h, w0p, b0p, nullptr, tmp, T);
      conv3_kernel<1, true ><<<dim3(T / 128, 4), 512, 0, stream>>>(tmp, w1p, b1p, h, h, T);
    }
  }

  // ---- VQ (T == 8192, z_e in h; 32768 tokens) ----
  nz_kernel<<<8192, 256, 0, stream>>>(h, nzbuf);
  vq_dots_kernel<<<dim3(32768 / VQA_TOKS, 2), 256, 0, stream>>>(h, cb, nzbuf, out + OFF_SIM, pmin);
  vq_finish_kernel<<<512, 256, 0, stream>>>(h, cb, pmin, tmp, out + OFF_IDS, blocksum);
  loss_fin_kernel<<<1, 64, 0, stream>>>(blocksum, out + OFF_LOSS);
  { float* s = h; h = tmp; tmp = s; }  // h = z_q

  // ---- decoder ----
  for (int blk = 0; blk < 3; ++blk) {
    for (int r = 0; r < 4; ++r) {
      const float* w0p = w_res_d + (((size_t)blk * 4 + r) * 2 + 0) * 3 * 64 * 64;
      const float* w1p = w_res_d + (((size_t)blk * 4 + r) * 2 + 1) * 3 * 64 * 64;
      const float* b0p = b_res_d + (((size_t)blk * 4 + r) * 2 + 0) * 64;
      const float* b1p = b_res_d + (((size_t)blk * 4 + r) * 2 + 1) * 64;
      conv3_kernel<1, false><<<dim3(T / 128, 4), 512, 0, stream>>>(h, w0p, b0p, nullptr, tmp, T);
      conv3_kernel<3, true ><<<dim3(T / 128, 4), 512, 0, stream>>>(tmp, w1p, b1p, h, h, T);
    }
    up_kernel<<<dim3(2 * T / 128, 4), 512, 0, stream>>>(
        h, w_up + (size_t)blk * 4 * 64 * 64, b_up + blk * 64, tmp, T);
    T <<= 1;
    float* s = h; h = tmp; tmp = s;
  }

  // ---- final projection (T == 65536) ----
  proj_kernel<<<1024, 256, 0, stream>>>(h, w_proj, b_proj, out);
}

// Round 7
// 1690.801 us; speedup vs baseline: 1.3612x; 1.0569x over previous
//
#include <hip/hip_runtime.h>
#include <cstdint>

// ---------------------------------------------------------------------------
// JukeboxAutoEncoder fp32, round 7.
// convs: 512-thr (8 waves x 8 wave-uniform co, s_load weights); lane covers
//   TPL consecutive t -> aligned ds_read_b64 x-loads (XS mod 8 == 4);
//   TT=128 for T>=16384, TT=64 for T=8192 (occupancy for small layers).
// vq_dots: round-4 version (LDS-staged z tile, broadcast reads, VGPR~64).
// Output layout (flat f32): x_hat[262144] | loss_vq[1] | ids[32768] | sim[16777216]
// ---------------------------------------------------------------------------

#define OFF_LOSS 262144
#define OFF_IDS  262145
#define OFF_SIM  294913

// ---------------- down0: (B,65536,1) -> (B,32768,64), K=4 stride2, relu ----
__global__ __launch_bounds__(256) void down0_kernel(
    const float* __restrict__ x, const float* __restrict__ w,
    const float* __restrict__ bias, float* __restrict__ y)
{
  int idx = blockIdx.x * 256 + threadIdx.x;   // enumerates (b, t, co)
  int co = idx & 63;
  int r  = idx >> 6;
  int t  = r & 32767;
  int b  = r >> 15;
  const float* xb = x + (size_t)b * 65536;
  float acc = bias[co];
  #pragma unroll
  for (int k = 0; k < 4; ++k) {
    int gt = 2 * t - 1 + k;
    float xv = ((unsigned)gt < 65536u) ? xb[gt] : 0.f;
    acc += xv * w[k * 64 + co];
  }
  y[(size_t)idx] = fmaxf(acc, 0.f);
}

// ---------------- conv3: K=3, dil DIL, 64->64, relu, optional +res --------
// 512 thr = 8 waves; wave wv owns co0 = wv*8 (wave-uniform -> s_load weights);
// lane covers t = t0 + TPL*lane + i, i<TPL. grid (T/TT, 4).
template <int DIL, bool HAS_RES, int TT>
__global__ __launch_bounds__(512, 8) void conv3_kernel(
    const float* __restrict__ x, const float* __restrict__ w,
    const float* __restrict__ bias, const float* res,
    float* y, int T)
{
  constexpr int TPL = TT / 64;               // 1 or 2 t per lane
  constexpr int XT  = TT + 2 * DIL;
  constexpr int XS0 = (XT + 3) & ~3;
  constexpr int XS  = (XS0 % 8 == 4) ? XS0 : XS0 + 4;  // 8B-align rows, break pow2
  constexpr int NV  = TPL + 2 * DIL;
  __shared__ float xs[64 * XS];
  const int tid  = threadIdx.x;
  const int lane = tid & 63;
  const int b    = blockIdx.y;
  const int t0   = blockIdx.x * TT;
  const int wv   = __builtin_amdgcn_readfirstlane(tid >> 6);
  const int co0  = __builtin_amdgcn_readfirstlane(wv * 8);

  const float* xb = x + (size_t)b * T * 64;
  for (int e = tid; e < 16 * XT; e += 512) { // transpose to [ci][t]
    int tl = e >> 4, cq = (e & 15) * 4;
    int gt = t0 - DIL + tl;
    float4 v = make_float4(0.f, 0.f, 0.f, 0.f);
    if ((unsigned)gt < (unsigned)T) v = *(const float4*)&xb[(size_t)gt * 64 + cq];
    xs[(cq + 0) * XS + tl] = v.x;
    xs[(cq + 1) * XS + tl] = v.y;
    xs[(cq + 2) * XS + tl] = v.z;
    xs[(cq + 3) * XS + tl] = v.w;
  }
  __syncthreads();

  float acc[TPL][8] = {};
  const float* wb = w + co0;                 // w[k][ci][co0..co0+7]
  const int tb = TPL * lane;
  for (int ci = 0; ci < 64; ++ci) {
    const float* xr = xs + ci * XS + tb;
    float xv[NV];
    if constexpr (TPL == 2) {                // 8B-aligned -> ds_read_b64
      const float2* p2 = (const float2*)xr;
      #pragma unroll
      for (int q = 0; q < NV / 2; ++q) { float2 v = p2[q]; xv[2*q] = v.x; xv[2*q+1] = v.y; }
    } else {
      #pragma unroll
      for (int j = 0; j < NV; ++j) xv[j] = xr[j];
    }
    const float* w0 = wb + (0 * 64 + ci) * 64;
    const float* w1 = wb + (1 * 64 + ci) * 64;
    const float* w2 = wb + (2 * 64 + ci) * 64;
    #pragma unroll
    for (int j = 0; j < 8; ++j) {
      float c0 = w0[j], c1 = w1[j], c2 = w2[j];
      #pragma unroll
      for (int i = 0; i < TPL; ++i)
        acc[i][j] = fmaf(xv[i], c0, fmaf(xv[i + DIL], c1, fmaf(xv[i + 2 * DIL], c2, acc[i][j])));
    }
  }

  float bs[8];
  #pragma unroll
  for (int j = 0; j < 8; ++j) bs[j] = bias[co0 + j];
  #pragma unroll
  for (int i = 0; i < TPL; ++i) {
    size_t o = ((size_t)b * T + t0 + tb + i) * 64 + co0;
    float r[8];
    #pragma unroll
    for (int j = 0; j < 8; ++j) r[j] = fmaxf(acc[i][j] + bs[j], 0.f);
    if (HAS_RES) {
      float4 v0 = *(const float4*)&res[o];
      float4 v1 = *(const float4*)&res[o + 4];
      r[0] += v0.x; r[1] += v0.y; r[2] += v0.z; r[3] += v0.w;
      r[4] += v1.x; r[5] += v1.y; r[6] += v1.z; r[7] += v1.w;
    }
    *(float4*)&y[o]     = make_float4(r[0], r[1], r[2], r[3]);
    *(float4*)&y[o + 4] = make_float4(r[4], r[5], r[6], r[7]);
  }
}

// ---------------- down2: K=4 stride2, 64->64, relu ------------------------
// 512 thr = 8 waves; wave owns co0 = wv*8; lane = out t (64/block).
// grid (Tout/64, 4). Reads 4 consecutive floats at 2*lane -> 2x ds_read_b64.
__global__ __launch_bounds__(512, 8) void down2_kernel(
    const float* __restrict__ x, const float* __restrict__ w,
    const float* __restrict__ bias, float* __restrict__ y, int Tin)
{
  constexpr int XT = 130, XS = 132;          // XS mod 8 == 4
  __shared__ float xs[64 * XS];
  const int tid  = threadIdx.x;
  const int lane = tid & 63;
  const int b    = blockIdx.y;
  const int t0   = blockIdx.x * 64;
  const int Tout = Tin >> 1;
  const int wv   = __builtin_amdgcn_readfirstlane(tid >> 6);
  const int co0  = __builtin_amdgcn_readfirstlane(wv * 8);

  const float* xb = x + (size_t)b * Tin * 64;
  for (int e = tid; e < 16 * XT; e += 512) {
    int tl = e >> 4, cq = (e & 15) * 4;
    int gt = 2 * t0 - 1 + tl;
    float4 v = make_float4(0.f, 0.f, 0.f, 0.f);
    if ((unsigned)gt < (unsigned)Tin) v = *(const float4*)&xb[(size_t)gt * 64 + cq];
    xs[(cq + 0) * XS + tl] = v.x;
    xs[(cq + 1) * XS + tl] = v.y;
    xs[(cq + 2) * XS + tl] = v.z;
    xs[(cq + 3) * XS + tl] = v.w;
  }
  __syncthreads();

  float acc[8] = {};
  const float* wb = w + co0;
  for (int ci = 0; ci < 64; ++ci) {
    const float2* p2 = (const float2*)(xs + ci * XS + 2 * lane);
    float2 v0 = p2[0], v1 = p2[1];
    float a0 = v0.x, a1 = v0.y, a2 = v1.x, a3 = v1.y;
    const float* w0 = wb + (0 * 64 + ci) * 64;
    const float* w1 = wb + (1 * 64 + ci) * 64;
    const float* w2 = wb + (2 * 64 + ci) * 64;
    const float* w3 = wb + (3 * 64 + ci) * 64;
    #pragma unroll
    for (int j = 0; j < 8; ++j)
      acc[j] = fmaf(a0, w0[j], fmaf(a1, w1[j], fmaf(a2, w2[j], fmaf(a3, w3[j], acc[j]))));
  }

  size_t o = ((size_t)b * Tout + t0 + lane) * 64 + co0;
  #pragma unroll
  for (int q = 0; q < 2; ++q) {
    float4 rr;
    rr.x = fmaxf(acc[4*q+0] + bias[co0 + 4*q+0], 0.f);
    rr.y = fmaxf(acc[4*q+1] + bias[co0 + 4*q+1], 0.f);
    rr.z = fmaxf(acc[4*q+2] + bias[co0 + 4*q+2], 0.f);
    rr.w = fmaxf(acc[4*q+3] + bias[co0 + 4*q+3], 0.f);
    *(float4*)&y[o + 4 * q] = rr;
  }
}

// ---------------- up: conv_transpose K=4 stride2, 64->64, relu ------------
// y[2u] = relu(b + w0^T x[u-1] + w2^T x[u]); y[2u+1] = relu(b + w1^T x[u] + w3^T x[u+1])
// 512 thr = 8 waves; wave owns co0 = wv*8; lane = u (64 u = 128 out t).
// grid (Tout/128, 4).
__global__ __launch_bounds__(512, 8) void up_kernel(
    const float* __restrict__ x, const float* __restrict__ w,
    const float* __restrict__ bias, float* __restrict__ y, int Tin)
{
  constexpr int XT = 66, XS = 68;            // XS mod 8 == 4
  __shared__ float xs[64 * XS];
  const int tid  = threadIdx.x;
  const int lane = tid & 63;
  const int b    = blockIdx.y;
  const int u0   = blockIdx.x * 64;
  const int Tout = Tin << 1;
  const int wv   = __builtin_amdgcn_readfirstlane(tid >> 6);
  const int co0  = __builtin_amdgcn_readfirstlane(wv * 8);

  const float* xb = x + (size_t)b * Tin * 64;
  for (int e = tid; e < 16 * XT; e += 512) {
    int ul = e >> 4, cq = (e & 15) * 4;
    int gu = u0 - 1 + ul;
    float4 v = make_float4(0.f, 0.f, 0.f, 0.f);
    if ((unsigned)gu < (unsigned)Tin) v = *(const float4*)&xb[(size_t)gu * 64 + cq];
    xs[(cq + 0) * XS + ul] = v.x;
    xs[(cq + 1) * XS + ul] = v.y;
    xs[(cq + 2) * XS + ul] = v.z;
    xs[(cq + 3) * XS + ul] = v.w;
  }
  __syncthreads();

  float acce[8] = {}, acco[8] = {};
  const float* wb = w + co0;
  for (int ci = 0; ci < 64; ++ci) {
    const float* xr = xs + ci * XS + lane;
    float a0 = xr[0], a1 = xr[1], a2 = xr[2];  // x[u-1], x[u], x[u+1]
    const float* w0 = wb + (0 * 64 + ci) * 64;
    const float* w1 = wb + (1 * 64 + ci) * 64;
    const float* w2 = wb + (2 * 64 + ci) * 64;
    const float* w3 = wb + (3 * 64 + ci) * 64;
    #pragma unroll
    for (int j = 0; j < 8; ++j) {
      acce[j] = fmaf(a0, w0[j], fmaf(a1, w2[j], acce[j]));
      acco[j] = fmaf(a1, w1[j], fmaf(a2, w3[j], acco[j]));
    }
  }

  size_t oe = ((size_t)b * Tout + 2 * (u0 + lane)) * 64 + co0;
  size_t oo = oe + 64;
  #pragma unroll
  for (int q = 0; q < 2; ++q) {
    float4 re, ro;
    re.x = fmaxf(acce[4*q+0] + bias[co0 + 4*q+0], 0.f);
    re.y = fmaxf(acce[4*q+1] + bias[co0 + 4*q+1], 0.f);
    re.z = fmaxf(acce[4*q+2] + bias[co0 + 4*q+2], 0.f);
    re.w = fmaxf(acce[4*q+3] + bias[co0 + 4*q+3], 0.f);
    ro.x = fmaxf(acco[4*q+0] + bias[co0 + 4*q+0], 0.f);
    ro.y = fmaxf(acco[4*q+1] + bias[co0 + 4*q+1], 0.f);
    ro.z = fmaxf(acco[4*q+2] + bias[co0 + 4*q+2], 0.f);
    ro.w = fmaxf(acco[4*q+3] + bias[co0 + 4*q+3], 0.f);
    *(float4*)&y[oe + 4 * q] = re;
    *(float4*)&y[oo + 4 * q] = ro;
  }
}

// ---------------- proj: K=3 dil1, 64->1, linear ---------------------------
__global__ __launch_bounds__(256) void proj_kernel(
    const float* __restrict__ x, const float* __restrict__ w,
    const float* __restrict__ bias, float* __restrict__ out)
{
  const int lane = threadIdx.x & 63;
  const int wid  = (blockIdx.x * 256 + threadIdx.x) >> 6;  // 4096 waves
  const float w0 = w[lane], w1 = w[64 + lane], w2 = w[128 + lane];
  const float bb = bias[0];
  size_t base = (size_t)wid * 64;
  for (int i = 0; i < 64; ++i) {
    size_t tau = base + i;
    int b = (int)(tau >> 16);
    int t = (int)(tau & 65535);
    const float* xb = x + ((size_t)b * 65536) * 64;
    float pm = (t > 0)     ? xb[(size_t)(t - 1) * 64 + lane] : 0.f;
    float pc =               xb[(size_t)t * 64 + lane];
    float pp = (t < 65535) ? xb[(size_t)(t + 1) * 64 + lane] : 0.f;
    float s = pm * w0 + pc * w1 + pp * w2;
    #pragma unroll
    for (int off = 32; off; off >>= 1) s += __shfl_down(s, off);
    if (lane == 0) out[tau] = s + bb;
  }
}

// ---------------- nz: per-token sum of squares ----------------------------
__global__ __launch_bounds__(256) void nz_kernel(
    const float* __restrict__ ze, float* __restrict__ nz)
{
  int lane = threadIdx.x & 63;
  int tok  = (blockIdx.x * 256 + threadIdx.x) >> 6;
  float v = ze[(size_t)tok * 64 + lane];
  float s = v * v;
  #pragma unroll
  for (int off = 32; off; off >>= 1) s += __shfl_down(s, off);
  if (lane == 0) nz[tok] = s;
}

// ---------------- vq_dots: round-4 version (LDS z tile, 1 cb row/thr) -----
#define VQA_TOKS 32
__global__ __launch_bounds__(256) void vq_dots_kernel(
    const float* __restrict__ ze, const float* __restrict__ cb,
    const float* __restrict__ nzbuf, float* __restrict__ sim_out,
    float2* __restrict__ pmin)
{
  __shared__ float zs[VQA_TOKS * 64];        // 8 KB
  const int tid = threadIdx.x;
  {
    const float4* src = (const float4*)(ze + (size_t)blockIdx.x * VQA_TOKS * 64);
    float4* dst = (float4*)zs;
    dst[tid]       = src[tid];
    dst[tid + 256] = src[tid + 256];
  }
  const int c = blockIdx.y * 256 + tid;
  float r[64];
  #pragma unroll
  for (int q = 0; q < 16; ++q) {
    float4 a = ((const float4*)cb)[(size_t)c * 16 + q];
    r[4*q] = a.x; r[4*q+1] = a.y; r[4*q+2] = a.z; r[4*q+3] = a.w;
  }
  float ne = 0.f;
  #pragma unroll
  for (int d = 0; d < 64; ++d) ne += r[d] * r[d];
  const float rsne = 1.f / sqrtf(ne);
  const int wvid = tid >> 6;
  __syncthreads();

  for (int it = 0; it < VQA_TOKS; ++it) {
    const int tok = blockIdx.x * VQA_TOKS + it;
    const float4* z4 = (const float4*)(zs + it * 64);   // LDS broadcast reads
    float dot = 0.f;
    #pragma unroll
    for (int q = 0; q < 16; ++q) {
      float4 zv = z4[q];
      dot += zv.x * r[4*q] + zv.y * r[4*q+1] + zv.z * r[4*q+2] + zv.w * r[4*q+3];
    }
    const float nzv = nzbuf[tok];
    float dist = (-2.f * dot + nzv) + ne;
    sim_out[(size_t)tok * 512 + c] = dot * (1.f / sqrtf(nzv)) * rsne;

    float md = dist; int mi = c;
    #pragma unroll
    for (int off = 32; off; off >>= 1) {
      float od = __shfl_down(md, off);
      int   oi = __shfl_down(mi, off);
      if (od < md || (od == md && oi < mi)) { md = od; mi = oi; }
    }
    if ((tid & 63) == 0) pmin[tok * 8 + blockIdx.y * 4 + wvid] = make_float2(md, (float)mi);
  }
}

// ---------------- vq_finish: cross-partial argmin, z_q, ids, loss ---------
__global__ __launch_bounds__(256) void vq_finish_kernel(
    const float* __restrict__ ze, const float* __restrict__ cb,
    const float2* __restrict__ pmin, float* __restrict__ zq,
    float* __restrict__ ids_out, float* __restrict__ blocksum)
{
  const int tid = threadIdx.x;
  const int lane = tid & 63, wvid = tid >> 6;
  float lloss = 0.f;
  for (int it = 0; it < 16; ++it) {
    const int tok = blockIdx.x * 64 + wvid * 16 + it;
    float bd = 1e30f; int bi = 0;
    #pragma unroll
    for (int p = 0; p < 8; ++p) {
      float2 pr = pmin[tok * 8 + p];
      float d = pr.x; int i = (int)pr.y;
      if (d < bd || (d == bd && i < bi)) { bd = d; bi = i; }
    }
    float zev = ze[(size_t)tok * 64 + lane];
    float cv  = cb[(size_t)bi * 64 + lane];
    float df = zev - cv;
    float s = df * df;
    #pragma unroll
    for (int off = 32; off; off >>= 1) s += __shfl_down(s, off);
    zq[(size_t)tok * 64 + lane] = cv;
    if (lane == 0) { ids_out[tok] = (float)bi; lloss += sqrtf(s); }
  }
  __shared__ float ls[4];
  if (lane == 0) ls[wvid] = lloss;
  __syncthreads();
  if (tid == 0) blocksum[blockIdx.x] = ls[0] + ls[1] + ls[2] + ls[3];
}

__global__ void loss_fin_kernel(const float* __restrict__ blocksum,
                                float* __restrict__ out)
{
  const int lane = threadIdx.x;  // 64 threads
  float s = 0.f;
  for (int i = lane; i < 512; i += 64) s += blocksum[i];
  #pragma unroll
  for (int off = 32; off; off >>= 1) s += __shfl_down(s, off);
  if (lane == 0) out[0] = 1.25f * s / 32768.f;
}

// ---------------------------------------------------------------------------
#define LAUNCH_CONV3(DILV, RESV, XP, WP, BP, RP, YP)                           \
  do {                                                                         \
    if (T >= 16384)                                                            \
      conv3_kernel<DILV, RESV, 128><<<dim3(T / 128, 4), 512, 0, stream>>>(     \
          XP, WP, BP, RP, YP, T);                                              \
    else                                                                       \
      conv3_kernel<DILV, RESV, 64><<<dim3(T / 64, 4), 512, 0, stream>>>(       \
          XP, WP, BP, RP, YP, T);                                              \
  } while (0)

extern "C" void kernel_launch(void* const* d_in, const int* in_sizes, int n_in,
                              void* d_out, int out_size, void* d_ws, size_t ws_size,
                              hipStream_t stream)
{
  const float* x       = (const float*)d_in[0];
  const float* w_down0 = (const float*)d_in[1];
  const float* b_down0 = (const float*)d_in[2];
  const float* w_down  = (const float*)d_in[3];
  const float* b_down  = (const float*)d_in[4];
  const float* w_res_e = (const float*)d_in[5];
  const float* b_res_e = (const float*)d_in[6];
  const float* cb      = (const float*)d_in[7];
  const float* w_res_d = (const float*)d_in[8];
  const float* b_res_d = (const float*)d_in[9];
  const float* w_up    = (const float*)d_in[10];
  const float* b_up    = (const float*)d_in[11];
  const float* w_proj  = (const float*)d_in[12];
  const float* b_proj  = (const float*)d_in[13];

  float* out = (float*)d_out;
  const size_t BUF = (size_t)4 * 65536 * 64;
  float*  bufA     = (float*)d_ws;
  float*  bufB     = bufA + BUF;
  float*  nzbuf    = bufB + BUF;
  float2* pmin     = (float2*)(nzbuf + 32768);
  float*  blocksum = (float*)(pmin + 32768 * 8);

  float* h = bufA;
  float* tmp = bufB;

  // ---- encoder ----
  down0_kernel<<<32768, 256, 0, stream>>>(x, w_down0, b_down0, h);
  int T = 32768;
  for (int blk = 0; blk < 3; ++blk) {
    if (blk > 0) {
      down2_kernel<<<dim3(T / 2 / 64, 4), 512, 0, stream>>>(
          h, w_down + (size_t)(blk - 1) * 4 * 64 * 64, b_down + (blk - 1) * 64, tmp, T);
      T >>= 1;
      float* s = h; h = tmp; tmp = s;
    }
    for (int r = 0; r < 4; ++r) {
      const float* w0p = w_res_e + (((size_t)blk * 4 + r) * 2 + 0) * 3 * 64 * 64;
      const float* w1p = w_res_e + (((size_t)blk * 4 + r) * 2 + 1) * 3 * 64 * 64;
      const float* b0p = b_res_e + (((size_t)blk * 4 + r) * 2 + 0) * 64;
      const float* b1p = b_res_e + (((size_t)blk * 4 + r) * 2 + 1) * 64;
      LAUNCH_CONV3(3, false, h, w0p, b0p, nullptr, tmp);
      LAUNCH_CONV3(1, true,  tmp, w1p, b1p, h, h);
    }
  }

  // ---- VQ (T == 8192, z_e in h; 32768 tokens) ----
  nz_kernel<<<8192, 256, 0, stream>>>(h, nzbuf);
  vq_dots_kernel<<<dim3(32768 / VQA_TOKS, 2), 256, 0, stream>>>(h, cb, nzbuf, out + OFF_SIM, pmin);
  vq_finish_kernel<<<512, 256, 0, stream>>>(h, cb, pmin, tmp, out + OFF_IDS, blocksum);
  loss_fin_kernel<<<1, 64, 0, stream>>>(blocksum, out + OFF_LOSS);
  { float* s = h; h = tmp; tmp = s; }  // h = z_q

  // ---- decoder ----
  for (int blk = 0; blk < 3; ++blk) {
    for (int r = 0; r < 4; ++r) {
      const float* w0p = w_res_d + (((size_t)blk * 4 + r) * 2 + 0) * 3 * 64 * 64;
      const float* w1p = w_res_d + (((size_t)blk * 4 + r) * 2 + 1) * 3 * 64 * 64;
      const float* b0p = b_res_d + (((size_t)blk * 4 + r) * 2 + 0) * 64;
      const float* b1p = b_res_d + (((size_t)blk * 4 + r) * 2 + 1) * 64;
      LAUNCH_CONV3(1, false, h, w0p, b0p, nullptr, tmp);
      LAUNCH_CONV3(3, true,  tmp, w1p, b1p, h, h);
    }
    up_kernel<<<dim3(2 * T / 128, 4), 512, 0, stream>>>(
        h, w_up + (size_t)blk * 4 * 64 * 64, b_up + blk * 64, tmp, T);
    T <<= 1;
    float* s = h; h = tmp; tmp = s;
  }

  // ---- final projection (T == 65536) ----
  proj_kernel<<<1024, 256, 0, stream>>>(h, w_proj, b_proj, out);
}